// Round 1
// baseline (2131.365 us; speedup 1.0000x reference)
//
#include <hip/hip_runtime.h>
#include <math.h>

// Problem constants (fixed by the reference)
#define NBATCH 16
#define CCH    128     // channels C
#define HW     2304    // 48*48 tokens per frame
#define DI     64      // inter_channels CI
#define NTILE  36      // HW / 64

// ws layout: q | k | v, each [N][HW][DI] fp32  -> 3 * 16*2304*64 * 4B = 28.3 MB

__device__ __forceinline__ float rl(float x, int lane) {
    return __int_as_float(__builtin_amdgcn_readlane(__float_as_int(x), lane));
}

// ---------------------------------------------------------------------------
// Kernel 1: fused q/k/v projection. t[n,p,d] = sum_c F[n,c,p] * W[d,c] + b[d]
// Block handles (n, 64 tokens). W^T staged in LDS; weights read once per
// c-chunk (not per token) by accumulating 16 tokens per wave in registers.
// ---------------------------------------------------------------------------
__global__ __launch_bounds__(256) void proj_kernel(
    const float* __restrict__ F,
    const float* __restrict__ Wq, const float* __restrict__ bq,
    const float* __restrict__ Wk, const float* __restrict__ bk,
    const float* __restrict__ Wv, const float* __restrict__ bv,
    float* __restrict__ qo, float* __restrict__ ko, float* __restrict__ vo)
{
    __shared__ __align__(16) float Ws[3][DI][132];   // [d][c], pad 132 for b128 reads
    const int tid = threadIdx.x;
    for (int idx = tid; idx < DI * CCH; idx += 256) {
        int d = idx >> 7, c = idx & 127;
        Ws[0][d][c] = Wq[idx];
        Ws[1][d][c] = Wk[idx];
        Ws[2][d][c] = Wv[idx];
    }
    __syncthreads();

    const int n    = blockIdx.x / NTILE;
    const int p0   = (blockIdx.x % NTILE) * 64;
    const int lane = tid & 63;                                   // = d
    const int wave = __builtin_amdgcn_readfirstlane(tid >> 6);
    const float* Fn = F + (size_t)n * CCH * HW;

    float aq[16], ak[16], av[16];
    const float bq_ = bq[lane], bk_ = bk[lane], bv_ = bv[lane];
    #pragma unroll
    for (int i = 0; i < 16; ++i) { aq[i] = bq_; ak[i] = bk_; av[i] = bv_; }

    const int pbase = p0 + wave * 16;
    for (int c4 = 0; c4 < 32; ++c4) {
        float4 wq4 = *(const float4*)&Ws[0][lane][c4 * 4];
        float4 wk4 = *(const float4*)&Ws[1][lane][c4 * 4];
        float4 wv4 = *(const float4*)&Ws[2][lane][c4 * 4];
        const float* F0 = Fn + (size_t)(c4 * 4) * HW + pbase;    // wave-uniform
        #pragma unroll
        for (int i = 0; i < 16; ++i) {
            float f0 = F0[i];
            float f1 = F0[HW + i];
            float f2 = F0[2 * HW + i];
            float f3 = F0[3 * HW + i];
            aq[i] += f0 * wq4.x + f1 * wq4.y + f2 * wq4.z + f3 * wq4.w;
            ak[i] += f0 * wk4.x + f1 * wk4.y + f2 * wk4.z + f3 * wk4.w;
            av[i] += f0 * wv4.x + f1 * wv4.y + f2 * wv4.z + f3 * wv4.w;
        }
    }
    #pragma unroll
    for (int i = 0; i < 16; ++i) {
        size_t off = (size_t)(n * HW + pbase + i) * DI + lane;   // coalesced (d=lane)
        qo[off] = aq[i]; ko[off] = ak[i]; vo[off] = av[i];
    }
}

// ---------------------------------------------------------------------------
// Kernel 2: flash-style two-neighbor attention + fused output projection.
// Block = (frame n, 64 q-rows); 4 waves x 16 rows. K/V tiles (64 rows) staged
// in LDS, shared by all waves. Online softmax; lane j owns K-row j for
// scores, lane d owns y[d] for the PV accumulation (P moved via v_readlane).
// z_b + z_a = (y_b/l_b + y_a/l_a) @ Wz^T + 2*bz  (+ residual F).
// ---------------------------------------------------------------------------
__global__ __launch_bounds__(256, 3) void attn_kernel(
    const float* __restrict__ q, const float* __restrict__ k, const float* __restrict__ v,
    const float* __restrict__ Wz, const float* __restrict__ bz,
    const float* __restrict__ F, float* __restrict__ out)
{
    __shared__ __align__(16) float qs[64 * 68];   // stride 68 floats = 272B (16B-aligned, odd/4)
    __shared__ __align__(16) float Ks[64 * 68];
    __shared__ __align__(16) float Vs[64 * 68];

    const int tid  = threadIdx.x;
    const int n    = blockIdx.x / NTILE;
    const int p0   = (blockIdx.x % NTILE) * 64;
    const int lane = tid & 63;
    const int wave = __builtin_amdgcn_readfirstlane(tid >> 6);

    // stage the 64x64 q tile
    #pragma unroll
    for (int s = 0; s < 4; ++s) {
        int idx = tid + s * 256;                  // float4 index 0..1023
        int row = idx >> 4, d4 = idx & 15;
        *(float4*)&qs[row * 68 + d4 * 4] =
            *(const float4*)&q[(size_t)(n * HW + p0 + row) * DI + d4 * 4];
    }

    const int r0 = wave * 16;
    float ytot[16];
    #pragma unroll
    for (int r = 0; r < 16; ++r) ytot[r] = 0.f;

    for (int pass = 0; pass < 2; ++pass) {
        const int nb = (pass == 0) ? (n > 0 ? n - 1 : 0)
                                   : (n < NBATCH - 1 ? n + 1 : NBATCH - 1);
        const float* kp = k + (size_t)nb * HW * DI;
        const float* vp = v + (size_t)nb * HW * DI;

        float m[16], l[16], y[16];
        #pragma unroll
        for (int r = 0; r < 16; ++r) { m[r] = -INFINITY; l[r] = 0.f; y[r] = 0.f; }

        for (int t = 0; t < NTILE; ++t) {
            __syncthreads();                       // previous tile fully consumed
            #pragma unroll
            for (int s = 0; s < 4; ++s) {
                int idx = tid + s * 256;
                int row = idx >> 4, d4 = idx & 15;
                *(float4*)&Ks[row * 68 + d4 * 4] =
                    *(const float4*)&kp[(size_t)(t * 64 + row) * DI + d4 * 4];
                *(float4*)&Vs[row * 68 + d4 * 4] =
                    *(const float4*)&vp[(size_t)(t * 64 + row) * DI + d4 * 4];
            }
            __syncthreads();

            // scores: sc[r] (held by lane j) = q[r0+r] . K[j]
            float sc[16];
            #pragma unroll
            for (int r = 0; r < 16; ++r) sc[r] = 0.f;
            const float* Krow = &Ks[lane * 68];
            #pragma unroll
            for (int d4 = 0; d4 < 16; ++d4) {
                float4 kk = *(const float4*)&Krow[d4 * 4];
                #pragma unroll
                for (int r = 0; r < 16; ++r) {
                    float4 qq = *(const float4*)&qs[(r0 + r) * 68 + d4 * 4];  // broadcast
                    sc[r] += qq.x * kk.x + qq.y * kk.y + qq.z * kk.z + qq.w * kk.w;
                }
            }

            // online softmax update per row
            float pj[16];
            #pragma unroll
            for (int r = 0; r < 16; ++r) {
                float mt = sc[r];
                #pragma unroll
                for (int off = 32; off > 0; off >>= 1) mt = fmaxf(mt, __shfl_xor(mt, off));
                float mn    = fmaxf(m[r], mt);
                float scale = __expf(m[r] - mn);
                float p     = __expf(sc[r] - mn);
                float su = p;
                #pragma unroll
                for (int off = 32; off > 0; off >>= 1) su += __shfl_xor(su, off);
                l[r] = l[r] * scale + su;
                m[r] = mn;
                y[r] *= scale;
                pj[r] = p;
            }

            // y[r] (held by lane d) += sum_j P[r][j] * V[j][d]
            #pragma unroll 4
            for (int j = 0; j < 64; ++j) {
                float vj = Vs[j * 68 + lane];      // conflict-free (odd stride)
                #pragma unroll
                for (int r = 0; r < 16; ++r)
                    y[r] += rl(pj[r], j) * vj;
            }
        }
        #pragma unroll
        for (int r = 0; r < 16; ++r) ytot[r] += y[r] / l[r];
    }

    // stage combined y, then fused z-projection + residual, coalesced store
    __syncthreads();
    float* ys = Ks;                                // reuse
    #pragma unroll
    for (int r = 0; r < 16; ++r) ys[(r0 + r) * 68 + lane] = ytot[r];
    __syncthreads();

    const int ploc = lane;
    const int cg   = wave;
    float acc[32];
    #pragma unroll
    for (int i = 0; i < 32; ++i) acc[i] = 0.f;
    #pragma unroll
    for (int d4 = 0; d4 < 16; ++d4) {
        float4 yy = *(const float4*)&ys[ploc * 68 + d4 * 4];
        #pragma unroll 8
        for (int i = 0; i < 32; ++i) {
            int c = cg + 4 * i;                    // wave-uniform -> scalar Wz loads
            float4 ww = *(const float4*)&Wz[c * DI + d4 * 4];
            acc[i] += yy.x * ww.x + yy.y * ww.y + yy.z * ww.z + yy.w * ww.w;
        }
    }
    #pragma unroll 4
    for (int i = 0; i < 32; ++i) {
        int c = cg + 4 * i;
        size_t gi = (size_t)(n * CCH + c) * HW + p0 + ploc;
        out[gi] = acc[i] + 2.f * bz[c] + F[gi];    // coalesced 256B store + residual
    }
}

extern "C" void kernel_launch(void* const* d_in, const int* in_sizes, int n_in,
                              void* d_out, int out_size, void* d_ws, size_t ws_size,
                              hipStream_t stream) {
    const float* F  = (const float*)d_in[0];
    const float* Wq = (const float*)d_in[1];
    const float* bq = (const float*)d_in[2];
    const float* Wk = (const float*)d_in[3];
    const float* bk = (const float*)d_in[4];
    const float* Wv = (const float*)d_in[5];
    const float* bv = (const float*)d_in[6];
    const float* Wz = (const float*)d_in[7];
    const float* bz = (const float*)d_in[8];
    float* outp = (float*)d_out;
    float* ws   = (float*)d_ws;

    const size_t tok = (size_t)NBATCH * HW * DI;   // 2,359,296 floats
    float* qb = ws;
    float* kb = ws + tok;
    float* vb = ws + 2 * tok;                      // needs 28.3 MB of ws

    proj_kernel<<<NBATCH * NTILE, 256, 0, stream>>>(F, Wq, bq, Wk, bk, Wv, bv, qb, kb, vb);
    attn_kernel<<<NBATCH * NTILE, 256, 0, stream>>>(qb, kb, vb, Wz, bz, F, outp);
}

// Round 2
// 255.229 us; speedup vs baseline: 8.3508x; 8.3508x over previous
//
#include <hip/hip_runtime.h>
#include <math.h>

// Problem constants (fixed by the reference)
#define NBATCH 16
#define CCH    128     // channels C
#define HW     2304    // 48*48 tokens per frame
#define DI     64      // inter_channels CI
#define NTILE  36      // HW / 64

typedef unsigned short u16;
typedef unsigned int   u32;
typedef __bf16 bf16x8 __attribute__((ext_vector_type(8)));
typedef float  f32x4  __attribute__((ext_vector_type(4)));

__device__ __forceinline__ u16 f2bf_rne(float x) {
    union { float f; u32 u; } v; v.f = x;
    u32 r = (v.u + 0x7FFFu + ((v.u >> 16) & 1u)) >> 16;
    return (u16)r;
}

// ---------------------------------------------------------------------------
// Kernel 1: fused q/k/v projection -> bf16.
// q,k stored [n][p][d]; v stored TRANSPOSED [n][d][p] (PV B-operand layout).
// ---------------------------------------------------------------------------
__global__ __launch_bounds__(256) void proj_kernel(
    const float* __restrict__ F,
    const float* __restrict__ Wq, const float* __restrict__ bq,
    const float* __restrict__ Wk, const float* __restrict__ bk,
    const float* __restrict__ Wv, const float* __restrict__ bv,
    u16* __restrict__ qo, u16* __restrict__ ko, u16* __restrict__ vto)
{
    __shared__ __align__(16) float Ws[3][DI][132];
    const int tid = threadIdx.x;
    for (int idx = tid; idx < DI * CCH; idx += 256) {
        int d = idx >> 7, c = idx & 127;
        Ws[0][d][c] = Wq[idx];
        Ws[1][d][c] = Wk[idx];
        Ws[2][d][c] = Wv[idx];
    }
    __syncthreads();

    const int n    = blockIdx.x / NTILE;
    const int p0   = (blockIdx.x % NTILE) * 64;
    const int lane = tid & 63;                                   // = d
    const int wave = __builtin_amdgcn_readfirstlane(tid >> 6);
    const float* Fn = F + (size_t)n * CCH * HW;

    float aq[16], ak[16], av[16];
    const float bq_ = bq[lane], bk_ = bk[lane], bv_ = bv[lane];
    #pragma unroll
    for (int i = 0; i < 16; ++i) { aq[i] = bq_; ak[i] = bk_; av[i] = bv_; }

    const int pbase = p0 + wave * 16;
    for (int c4 = 0; c4 < 32; ++c4) {
        float4 wq4 = *(const float4*)&Ws[0][lane][c4 * 4];
        float4 wk4 = *(const float4*)&Ws[1][lane][c4 * 4];
        float4 wv4 = *(const float4*)&Ws[2][lane][c4 * 4];
        const float* F0 = Fn + (size_t)(c4 * 4) * HW + pbase;
        #pragma unroll
        for (int i = 0; i < 16; ++i) {
            float f0 = F0[i];
            float f1 = F0[HW + i];
            float f2 = F0[2 * HW + i];
            float f3 = F0[3 * HW + i];
            aq[i] += f0 * wq4.x + f1 * wq4.y + f2 * wq4.z + f3 * wq4.w;
            ak[i] += f0 * wk4.x + f1 * wk4.y + f2 * wk4.z + f3 * wk4.w;
            av[i] += f0 * wv4.x + f1 * wv4.y + f2 * wv4.z + f3 * wv4.w;
        }
    }
    #pragma unroll
    for (int i = 0; i < 16; ++i) {
        size_t off = (size_t)(n * HW + pbase + i) * DI + lane;   // coalesced (d=lane)
        qo[off] = f2bf_rne(aq[i]);
        ko[off] = f2bf_rne(ak[i]);
    }
    // v transposed: row d=lane, 16 consecutive tokens -> 2x16B per lane
    union { u16 s[16]; uint4 v[2]; } pk;
    #pragma unroll
    for (int i = 0; i < 16; ++i) pk.s[i] = f2bf_rne(av[i]);
    size_t vo_off = ((size_t)n * DI + lane) * HW + pbase;
    *(uint4*)&vto[vo_off]     = pk.v[0];
    *(uint4*)&vto[vo_off + 8] = pk.v[1];
}

// ---------------------------------------------------------------------------
// Kernel 2: MFMA flash attention (no-max softmax: fp32 exp range is safe) +
// fused z-projection + residual.
// Block = (frame, 64 q-rows); 4 waves x 16 q-rows. KV tile = 64 keys.
// Per wave per tile: 8 mfma QK^T, exp, P->LDS(bf16), 8 mfma PV.
// ---------------------------------------------------------------------------
__global__ __launch_bounds__(256) void attn_kernel(
    const u16* __restrict__ q, const u16* __restrict__ k, const u16* __restrict__ vt,
    const float* __restrict__ Wz, const float* __restrict__ bz,
    const float* __restrict__ F, float* __restrict__ out)
{
    __shared__ __align__(16) u16 smem[13824];     // 27648 B
    u16* Ks = smem;                               // [64][72] bf16  (K rows)
    u16* Vs = smem + 64 * 72;                     // [64][72] bf16  (V^T: [d][key])

    const int tid  = threadIdx.x;
    const int lane = tid & 63;
    const int wave = tid >> 6;
    const int bid  = (int)blockIdx.x;
    const int swz  = (bid & 7) * 72 + (bid >> 3); // 576 = 8*72, bijective XCD swizzle
    const int n    = swz / NTILE;
    const int p0   = (swz % NTILE) * 64;
    const int lo   = lane & 15, hi = lane >> 4;

    u16* Pw = smem + 2 * 64 * 72 + wave * 16 * 72;  // per-wave P [16 q][72]

    // Q fragments (A-layout): lane holds Q[q=lo][d=hi*8+j], two 32-d k-steps
    bf16x8 qf0, qf1;
    {
        const u16* qp = q + ((size_t)n * HW + p0 + wave * 16 + lo) * DI + hi * 8;
        qf0 = *(const bf16x8*)qp;
        qf1 = *(const bf16x8*)(qp + 32);
    }

    // staging: 512 x 16B chunks per tile; thread covers chunks tid, tid+256
    const int srow0 = tid >> 3;              // 0..31
    const int srow1 = srow0 + 32;            // 32..63
    const int scol  = (tid & 7) * 8;         // element offset within row

    f32x4 ytot[4];
    #pragma unroll
    for (int nf = 0; nf < 4; ++nf)
        #pragma unroll
        for (int r = 0; r < 4; ++r) ytot[nf][r] = 0.f;

    uint4 kst0, kst1, vst0, vst1;

    #pragma unroll 1
    for (int pass = 0; pass < 2; ++pass) {
        const int nb = (pass == 0) ? (n > 0 ? n - 1 : 0)
                                   : (n < NBATCH - 1 ? n + 1 : n);
        const u16* kp = k  + (size_t)nb * HW * DI;
        const u16* vp = vt + (size_t)nb * DI * HW;

        f32x4 yacc[4];
        float lacc[4];
        #pragma unroll
        for (int r = 0; r < 4; ++r) lacc[r] = 0.f;
        #pragma unroll
        for (int nf = 0; nf < 4; ++nf)
            #pragma unroll
            for (int r = 0; r < 4; ++r) yacc[nf][r] = 0.f;

        // prologue: stage tile 0 into regs
        kst0 = *(const uint4*)(kp + (size_t)srow0 * DI + scol);
        kst1 = *(const uint4*)(kp + (size_t)srow1 * DI + scol);
        vst0 = *(const uint4*)(vp + (size_t)srow0 * HW + scol);
        vst1 = *(const uint4*)(vp + (size_t)srow1 * HW + scol);

        #pragma unroll 1
        for (int t = 0; t < NTILE; ++t) {
            __syncthreads();                       // prev tile fully consumed
            *(uint4*)&Ks[srow0 * 72 + scol] = kst0;
            *(uint4*)&Ks[srow1 * 72 + scol] = kst1;
            *(uint4*)&Vs[srow0 * 72 + scol] = vst0;
            *(uint4*)&Vs[srow1 * 72 + scol] = vst1;
            __syncthreads();
            if (t + 1 < NTILE) {                   // issue next-tile loads early
                const int t1 = (t + 1) * 64;
                kst0 = *(const uint4*)(kp + (size_t)(t1 + srow0) * DI + scol);
                kst1 = *(const uint4*)(kp + (size_t)(t1 + srow1) * DI + scol);
                vst0 = *(const uint4*)(vp + (size_t)srow0 * HW + t1 + scol);
                vst1 = *(const uint4*)(vp + (size_t)srow1 * HW + t1 + scol);
            }

            // --- QK^T: S[16 q][64 key], C-layout frags ---
            f32x4 sacc[4];
            #pragma unroll
            for (int nf = 0; nf < 4; ++nf) {
                #pragma unroll
                for (int r = 0; r < 4; ++r) sacc[nf][r] = 0.f;
                bf16x8 kf0 = *(const bf16x8*)&Ks[(nf * 16 + lo) * 72 + hi * 8];
                bf16x8 kf1 = *(const bf16x8*)&Ks[(nf * 16 + lo) * 72 + 32 + hi * 8];
                sacc[nf] = __builtin_amdgcn_mfma_f32_16x16x32_bf16(qf0, kf0, sacc[nf], 0, 0, 0);
                sacc[nf] = __builtin_amdgcn_mfma_f32_16x16x32_bf16(qf1, kf1, sacc[nf], 0, 0, 0);
            }

            // --- P = exp(S) (no max subtraction; fp32 range safe) ---
            // lane holds S[q = hi*4+r][key = nf*16+lo]; l accumulated from the
            // bf16-rounded P so P/l self-normalizes the quantization.
            #pragma unroll
            for (int nf = 0; nf < 4; ++nf) {
                #pragma unroll
                for (int r = 0; r < 4; ++r) {
                    union { float f; u32 u; } cv;
                    cv.f = __expf(sacc[nf][r]);
                    u16 pb = (u16)(cv.u >> 16);    // truncate to bf16
                    cv.u = (u32)pb << 16;
                    lacc[r] += cv.f;
                    Pw[(hi * 4 + r) * 72 + nf * 16 + lo] = pb;
                }
            }

            // --- PV: Y += P(16x64) x V(64x64) ---
            bf16x8 pa0 = *(const bf16x8*)&Pw[lo * 72 + hi * 8];        // keys 0..31
            bf16x8 pa1 = *(const bf16x8*)&Pw[lo * 72 + 32 + hi * 8];   // keys 32..63
            #pragma unroll
            for (int nf = 0; nf < 4; ++nf) {
                bf16x8 vf0 = *(const bf16x8*)&Vs[(nf * 16 + lo) * 72 + hi * 8];
                bf16x8 vf1 = *(const bf16x8*)&Vs[(nf * 16 + lo) * 72 + 32 + hi * 8];
                yacc[nf] = __builtin_amdgcn_mfma_f32_16x16x32_bf16(pa0, vf0, yacc[nf], 0, 0, 0);
                yacc[nf] = __builtin_amdgcn_mfma_f32_16x16x32_bf16(pa1, vf1, yacc[nf], 0, 0, 0);
            }
        }

        // l: reduce across lo lanes (keys); combine pass into ytot
        #pragma unroll
        for (int r = 0; r < 4; ++r) {
            float l = lacc[r];
            l += __shfl_xor(l, 1);
            l += __shfl_xor(l, 2);
            l += __shfl_xor(l, 4);
            l += __shfl_xor(l, 8);
            float inv = 1.f / l;
            #pragma unroll
            for (int nf = 0; nf < 4; ++nf) ytot[nf][r] += yacc[nf][r] * inv;
        }
    }

    // ---- fused z-projection + residual ----
    __syncthreads();
    float* ys = (float*)smem;                      // [64 tok][68 d] fp32
    #pragma unroll
    for (int nf = 0; nf < 4; ++nf)
        #pragma unroll
        for (int r = 0; r < 4; ++r)
            ys[(wave * 16 + hi * 4 + r) * 68 + nf * 16 + lo] = ytot[nf][r];
    __syncthreads();

    float acc[32];
    #pragma unroll
    for (int i = 0; i < 32; ++i) acc[i] = 0.f;
    #pragma unroll
    for (int d4 = 0; d4 < 16; ++d4) {
        float4 yy = *(const float4*)&ys[lane * 68 + d4 * 4];
        #pragma unroll 8
        for (int i = 0; i < 32; ++i) {
            int c = wave + 4 * i;                  // wave-uniform -> scalar Wz loads
            float4 ww = *(const float4*)&Wz[c * DI + d4 * 4];
            acc[i] += yy.x * ww.x + yy.y * ww.y + yy.z * ww.z + yy.w * ww.w;
        }
    }
    #pragma unroll 4
    for (int i = 0; i < 32; ++i) {
        int c = wave + 4 * i;
        size_t gi = (size_t)(n * CCH + c) * HW + p0 + lane;
        out[gi] = acc[i] + 2.f * bz[c] + F[gi];    // coalesced store + residual
    }
}

extern "C" void kernel_launch(void* const* d_in, const int* in_sizes, int n_in,
                              void* d_out, int out_size, void* d_ws, size_t ws_size,
                              hipStream_t stream) {
    const float* F  = (const float*)d_in[0];
    const float* Wq = (const float*)d_in[1];
    const float* bq = (const float*)d_in[2];
    const float* Wk = (const float*)d_in[3];
    const float* bk = (const float*)d_in[4];
    const float* Wv = (const float*)d_in[5];
    const float* bv = (const float*)d_in[6];
    const float* Wz = (const float*)d_in[7];
    const float* bz = (const float*)d_in[8];
    float* outp = (float*)d_out;

    const size_t tok = (size_t)NBATCH * HW * DI;   // 2,359,296 elements
    u16* qb  = (u16*)d_ws;
    u16* kb  = qb + tok;
    u16* vtb = kb + tok;                           // 14.2 MB of ws total

    proj_kernel<<<NBATCH * NTILE, 256, 0, stream>>>(F, Wq, bq, Wk, bk, Wv, bv, qb, kb, vtb);
    attn_kernel<<<NBATCH * NTILE, 256, 0, stream>>>(qb, kb, vtb, Wz, bz, F, outp);
}